// Round 2
// baseline (31622.940 us; speedup 1.0000x reference)
//
#include <hip/hip_runtime.h>
#include <hip/hip_bf16.h>
#include <stdint.h>

typedef unsigned int u32;
typedef unsigned long long u64;
typedef __attribute__((ext_vector_type(8))) short short8;
typedef __attribute__((ext_vector_type(4))) float floatx4;

#define T_STEPS 4096
#define BATCH   15
#define N_IN    512
#define N_H     1024
#define G_LAUNCH 64          // launched scan WGs; 8 elected (one XCD) participate
#define THREADS 512
#define HTAG_WORDS (15*512)  // tagged words per h buffer (15 batches x 512 pairs)
#define LDS_ROW 516          // u32 per h row: 512 + 4 pad
#define SC0_ROUNDS 8         // sc0 poll rounds before agent-scope fallback

// ---------- ws layout (bytes) ----------
#define OFF_XP    0
#define OFF_WIHB  (134217728)
#define OFF_HTAG  (134217728 + 1048576)
#define OFF_CLAIM (134217728 + 1048576 + 2*HTAG_WORDS*8)   // u32[16]: 8 counters + winner

__device__ inline u32 f2bf1(float f) {            // fp32 -> bf16 (RNE), as u32
    u32 u = __builtin_bit_cast(u32, f);
    return (u + 0x7FFFu + ((u >> 16) & 1u)) >> 16;
}
__device__ inline float bf2f(u32 us) {            // bf16 (low 16) -> fp32
    return __builtin_bit_cast(float, us << 16);
}
__device__ inline float tanh_fast(float x) {
    float e = __expf(2.0f * x);                   // inf-safe at both ends
    return 1.0f - 2.0f / (e + 1.0f);
}
// Agent-scope poll load (L2-bypassing, IC round-trip) — proven-correct fallback.
__device__ inline u64 mb_load(const u64* p) {
    return __hip_atomic_load(p, __ATOMIC_RELAXED, __HIP_MEMORY_SCOPE_AGENT);
}
// Publish store: plain/workgroup scope — dirty line in the local XCD L2,
// never written through to IC/HBM (R4: WRITE_SIZE 247 MB -> 2 MB).
__device__ inline void pub_store(u64* p, u64 v) {
    __hip_atomic_store(p, v, __ATOMIC_RELAXED, __HIP_MEMORY_SCOPE_WORKGROUP);
}

// Fast poll: sc0-only loads (bypass L1, HIT the shared same-XCD L2 where the
// publisher's write-through store landed). SGPR base + u32 voffset addressing;
// EARLY-CLOBBER outputs so no dest pair can alias a later load's operand
// (async VMEM returns have no WAR interlock — the R1 failure mode).
__device__ inline void poll15_sc0(const u64* sb, const u32 off[15], u64 v[15]) {
    asm volatile(
        "global_load_dwordx2 %0,  %15, %30 sc0\n\t"
        "global_load_dwordx2 %1,  %16, %30 sc0\n\t"
        "global_load_dwordx2 %2,  %17, %30 sc0\n\t"
        "global_load_dwordx2 %3,  %18, %30 sc0\n\t"
        "global_load_dwordx2 %4,  %19, %30 sc0\n\t"
        "global_load_dwordx2 %5,  %20, %30 sc0\n\t"
        "global_load_dwordx2 %6,  %21, %30 sc0\n\t"
        "global_load_dwordx2 %7,  %22, %30 sc0\n\t"
        "global_load_dwordx2 %8,  %23, %30 sc0\n\t"
        "global_load_dwordx2 %9,  %24, %30 sc0\n\t"
        "global_load_dwordx2 %10, %25, %30 sc0\n\t"
        "global_load_dwordx2 %11, %26, %30 sc0\n\t"
        "global_load_dwordx2 %12, %27, %30 sc0\n\t"
        "global_load_dwordx2 %13, %28, %30 sc0\n\t"
        "global_load_dwordx2 %14, %29, %30 sc0\n\t"
        "s_waitcnt vmcnt(0)"
        : "=&v"(v[0]), "=&v"(v[1]), "=&v"(v[2]), "=&v"(v[3]), "=&v"(v[4]),
          "=&v"(v[5]), "=&v"(v[6]), "=&v"(v[7]), "=&v"(v[8]), "=&v"(v[9]),
          "=&v"(v[10]), "=&v"(v[11]), "=&v"(v[12]), "=&v"(v[13]), "=&v"(v[14])
        : "v"(off[0]), "v"(off[1]), "v"(off[2]), "v"(off[3]), "v"(off[4]),
          "v"(off[5]), "v"(off[6]), "v"(off[7]), "v"(off[8]), "v"(off[9]),
          "v"(off[10]), "v"(off[11]), "v"(off[12]), "v"(off[13]), "v"(off[14]),
          "s"(sb)
        : "memory");
}

// ---------------- kernel 0: convert W_ih to packed bf16 (+ zero election block) ----------------
__global__ void k_cvt_wih(const float* __restrict__ W_ih, u32* __restrict__ wihb,
                          u32* __restrict__ claim) {
    if (blockIdx.x == 0 && threadIdx.x < 16) claim[threadIdx.x] = 0;
    int row = blockIdx.x;
    int tid = threadIdx.x;
    const float* p = W_ih + (size_t)row * N_IN + tid * 2;
    u32 packed = f2bf1(p[0]) | (f2bf1(p[1]) << 16);
    wihb[row * (N_IN / 2) + tid] = packed;
}

// ---------------- kernel 1: x_proj GEMM ----------------
// xp[((t*64 + cw)*64 + lane)] = bf16x4 (rows quad*4+i, col cw*16+(l&15))
__global__ void __launch_bounds__(256) k_xproj(
        const float* __restrict__ x, const u32* __restrict__ wihb,
        const float* __restrict__ b_ih, const float* __restrict__ b_hh,
        u64* __restrict__ xp) {
    const int t     = blockIdx.x;
    const int slice = blockIdx.y;
    const int tid   = threadIdx.x;
    const int wave  = tid >> 6;
    const int l     = tid & 63;
    const int row   = l & 15;       // batch
    const int quad  = l >> 4;
    const int colbase = slice * 256 + wave * 64;

    floatx4 acc[4] = {{0,0,0,0},{0,0,0,0},{0,0,0,0},{0,0,0,0}};
    const float* xrow = x + ((size_t)row * T_STEPS + t) * N_IN;

    #pragma unroll
    for (int kk = 0; kk < 16; ++kk) {
        short8 a;
        if (row < 15) {
            const float* pa = xrow + kk * 32 + quad * 8;
            float4 x0 = *(const float4*)(pa);
            float4 x1 = *(const float4*)(pa + 4);
            a[0]=(short)f2bf1(x0.x); a[1]=(short)f2bf1(x0.y); a[2]=(short)f2bf1(x0.z); a[3]=(short)f2bf1(x0.w);
            a[4]=(short)f2bf1(x1.x); a[5]=(short)f2bf1(x1.y); a[6]=(short)f2bf1(x1.z); a[7]=(short)f2bf1(x1.w);
        } else {
            #pragma unroll
            for (int j = 0; j < 8; ++j) a[j] = 0;
        }
        #pragma unroll
        for (int c4 = 0; c4 < 4; ++c4) {
            int col = colbase + c4 * 16 + (l & 15);
            const uint4* pb = (const uint4*)(wihb + (size_t)col * (N_IN/2) + kk * 16 + quad * 4);
            short8 b = __builtin_bit_cast(short8, *pb);
            acc[c4] = __builtin_amdgcn_mfma_f32_16x16x32_bf16(a, b, acc[c4], 0, 0, 0);
        }
    }
    #pragma unroll
    for (int c4 = 0; c4 < 4; ++c4) {
        int col = colbase + c4 * 16 + (l & 15);
        float bias = b_ih[col] + b_hh[col];
        u64 packed = (u64)f2bf1(acc[c4][0] + bias)
                   | ((u64)f2bf1(acc[c4][1] + bias) << 16)
                   | ((u64)f2bf1(acc[c4][2] + bias) << 32)
                   | ((u64)f2bf1(acc[c4][3] + bias) << 48);
        int cw = slice * 16 + wave * 4 + c4;
        xp[((size_t)t * 64 + cw) * 64 + l] = packed;
    }
}

// ---------------- kernel 2: sequential scan (8 elected WGs on ONE XCD) ----------------
__global__ void __launch_bounds__(THREADS, 2) k_scan(
        const float* __restrict__ W_hh, const u64* __restrict__ xp,
        u64* __restrict__ htag, u32* __restrict__ claim,
        const float* __restrict__ W_fc, const float* __restrict__ b_fc,
        float* __restrict__ out) {
    __shared__ u32 h_lds[2][16 * LDS_ROW];   // ping-pong h (bf16 pairs), row 15 = zero pad
    __shared__ float red[256];
    __shared__ int s_slot;
    __shared__ int s_dead;

    const int tid  = threadIdx.x;      // 0..511
    const int wave = tid >> 6;
    const int l    = tid & 63;
    const int c    = l & 15;           // col-in-tile (B/C role) == batch (A role)
    const int quad = l >> 4;

    // ---- XCD election: 8 co-XCD WGs win; others exit ----
    if (tid == 0) {
        u32 xcd;
        asm volatile("s_getreg_b32 %0, hwreg(HW_REG_XCC_ID)" : "=s"(xcd));
        xcd &= 7u;
        u32 slot = __hip_atomic_fetch_add(&claim[xcd], 1u, __ATOMIC_RELAXED,
                                          __HIP_MEMORY_SCOPE_AGENT);
        if (slot == 7u) {
            u32 exp = 0u;
            __hip_atomic_compare_exchange_strong(&claim[8], &exp, xcd + 1u,
                __ATOMIC_RELAXED, __ATOMIC_RELAXED, __HIP_MEMORY_SCOPE_AGENT);
        }
        u32 w = 0; int gg = 0;
        do { w = __hip_atomic_load(&claim[8], __ATOMIC_RELAXED, __HIP_MEMORY_SCOPE_AGENT); }
        while (!w && ++gg < (1 << 22));
        s_slot = (w == xcd + 1u && slot < 8u) ? (int)slot : -1;
        s_dead = 0;
    }
    __syncthreads();
    const int g = s_slot;              // 0..7 for participants
    if (g < 0) return;

    const int col  = g * 128 + wave * 16 + c;
    const int cw   = g * 8 + wave;

    // --- W_hh fragments permanently in registers (AGPR-resident) ---
    short8 wf[32];
    {
        const float* wr = W_hh + (size_t)col * N_H;
        #pragma unroll
        for (int kk = 0; kk < 32; ++kk) {
            const float* p = wr + kk * 32 + quad * 8;
            float4 w0 = *(const float4*)(p);
            float4 w1 = *(const float4*)(p + 4);
            short8 bfr;
            bfr[0]=(short)f2bf1(w0.x); bfr[1]=(short)f2bf1(w0.y); bfr[2]=(short)f2bf1(w0.z); bfr[3]=(short)f2bf1(w0.w);
            bfr[4]=(short)f2bf1(w1.x); bfr[5]=(short)f2bf1(w1.y); bfr[6]=(short)f2bf1(w1.z); bfr[7]=(short)f2bf1(w1.w);
            wf[kk] = bfr;
        }
    }
    for (int i = tid; i < 2 * 16 * LDS_ROW; i += THREADS) ((u32*)h_lds)[i] = 0;
    __syncthreads();

    // Loop-invariant poll byte-offsets (vs sc0-poll SGPR base).
    u32 poff[15];
    #pragma unroll
    for (int j = 0; j < 15; ++j) poff[j] = (u32)(tid * 8 + j * 4096);

    // ---- step 0: h(1) = tanh(xp(0)); publish tag 1 (parity 1) ----
    u64 xpw = xp[((size_t)0 * 64 + cw) * 64 + l];
    float h[4];
    {
        h[0] = tanh_fast(bf2f((u32)(xpw      ) & 0xFFFFu));
        h[1] = tanh_fast(bf2f((u32)(xpw >> 16) & 0xFFFFu));
        h[2] = tanh_fast(bf2f((u32)(xpw >> 32) & 0xFFFFu));
        h[3] = tanh_fast(bf2f((u32)(xpw >> 48) & 0xFFFFu));
        u64* bufw = htag + (size_t)1 * HTAG_WORDS;
        #pragma unroll
        for (int i = 0; i < 4; ++i) {
            int bt = quad * 4 + i;
            float o = __shfl_xor(h[i], 1);
            if (!(c & 1) && bt < 15) {
                u32 data = f2bf1(h[i]) | (f2bf1(o) << 16);
                pub_store(bufw + bt * 512 + (col >> 1), ((u64)1u << 32) | (u64)data);
            }
        }
    }
    u64 xpw_n = xp[((size_t)1 * 64 + cw) * 64 + l];

    for (int s = 1; s < T_STEPS; ++s) {
        xpw = xpw_n;
        const u64* buf = htag + (size_t)(s & 1) * HTAG_WORDS;
        u32* lds = &h_lds[s & 1][0];
        const u32 tag = (u32)s;

        // ---- poll: sc0 batched rounds; agent-scope fallback after SC0_ROUNDS ----
        u64 v[15];
        u32 got = 0;
        int rounds = 0;
        while (true) {
            if (rounds < SC0_ROUNDS) {
                poll15_sc0(buf, poff, v);
            } else {
                #pragma unroll
                for (int j = 0; j < 15; ++j)
                    if (!((got >> j) & 1)) v[j] = mb_load(buf + tid + j * 512);
            }
            #pragma unroll
            for (int j = 0; j < 15; ++j) {
                if (!((got >> j) & 1) && (u32)(v[j] >> 32) == tag) {
                    got |= 1u << j;
                    u32 w = (u32)tid + (u32)j * 512u;
                    lds[(w >> 9) * LDS_ROW + (w & 511)] = (u32)v[j];
                }
            }
            if (got == 0x7FFFu) break;
            if (++rounds > (1 << 20)) { s_dead = 1; break; }
        }
        __syncthreads();               // the ONLY barrier per step
        if (s_dead) break;

        // ---- compute: fully-unrolled dual-accumulator MFMA chain ----
        floatx4 acc0, acc1;
        acc0[0] = bf2f((u32)(xpw      ) & 0xFFFFu);
        acc0[1] = bf2f((u32)(xpw >> 16) & 0xFFFFu);
        acc0[2] = bf2f((u32)(xpw >> 32) & 0xFFFFu);
        acc0[3] = bf2f((u32)(xpw >> 48) & 0xFFFFu);
        acc1[0] = 0.f; acc1[1] = 0.f; acc1[2] = 0.f; acc1[3] = 0.f;

        #pragma unroll
        for (int t = 0; t < 16; ++t) {
            uint4 a0 = *(const uint4*)&lds[c * LDS_ROW + (2 * t    ) * 16 + quad * 4];
            uint4 a1 = *(const uint4*)&lds[c * LDS_ROW + (2 * t + 1) * 16 + quad * 4];
            acc0 = __builtin_amdgcn_mfma_f32_16x16x32_bf16(
                       __builtin_bit_cast(short8, a0), wf[2 * t    ], acc0, 0, 0, 0);
            acc1 = __builtin_amdgcn_mfma_f32_16x16x32_bf16(
                       __builtin_bit_cast(short8, a1), wf[2 * t + 1], acc1, 0, 0, 0);
        }

        if (s + 1 < T_STEPS) xpw_n = xp[((size_t)(s + 1) * 64 + cw) * 64 + l];

        #pragma unroll
        for (int i = 0; i < 4; ++i) h[i] = tanh_fast(acc0[i] + acc1[i]);

        // ---- publish h(s+1): plain stores -> dirty lines in the shared local L2 ----
        u64* bufw = htag + (size_t)((s + 1) & 1) * HTAG_WORDS;
        const u32 tag1 = (u32)(s + 1);
        #pragma unroll
        for (int i = 0; i < 4; ++i) {
            int bt = quad * 4 + i;
            float o = __shfl_xor(h[i], 1);
            if (!(c & 1) && bt < 15) {
                u32 data = f2bf1(h[i]) | (f2bf1(o) << 16);
                pub_store(bufw + bt * 512 + (col >> 1), ((u64)tag1 << 32) | (u64)data);
            }
        }
    }

    // ---------------- epilogue: elected WG 0 computes the sigmoid head ----------------
    if (g == 0) {
        const u64* fbuf = htag + (size_t)(T_STEPS & 1) * HTAG_WORDS;  // parity 0
        const u32 ftag = (u32)T_STEPS;
        u32* lds = &h_lds[0][0];
        u64 v[15];
        u32 got = 0;
        int rounds = 0;
        while (true) {
            if (rounds < SC0_ROUNDS) {
                poll15_sc0(fbuf, poff, v);
            } else {
                #pragma unroll
                for (int j = 0; j < 15; ++j)
                    if (!((got >> j) & 1)) v[j] = mb_load(fbuf + tid + j * 512);
            }
            #pragma unroll
            for (int j = 0; j < 15; ++j) {
                if (!((got >> j) & 1) && (u32)(v[j] >> 32) == ftag) {
                    got |= 1u << j;
                    u32 w = (u32)tid + (u32)j * 512u;
                    lds[(w >> 9) * LDS_ROW + (w & 511)] = (u32)v[j];
                }
            }
            if (got == 0x7FFFu) break;
            if (++rounds > (1 << 20)) break;
        }
        __syncthreads();
        if (tid < 240) {
            int b = tid >> 4, seg = tid & 15;
            float sum = 0.f;
            for (int j = 0; j < 64; ++j) {
                int k = seg * 64 + j;
                u32 pr = lds[b * LDS_ROW + (k >> 1)];
                float hv = bf2f((pr >> ((k & 1) * 16)) & 0xFFFFu);
                sum += hv * W_fc[k];
            }
            red[tid] = sum;
        }
        __syncthreads();
        if (tid < 15) {
            float z = 0.f;
            #pragma unroll
            for (int j = 0; j < 16; ++j) z += red[tid * 16 + j];
            z += b_fc[0];
            out[tid] = 1.0f / (1.0f + __expf(-z));
        }
    }
}

extern "C" void kernel_launch(void* const* d_in, const int* in_sizes, int n_in,
                              void* d_out, int out_size, void* d_ws, size_t ws_size,
                              hipStream_t stream) {
    const float* x    = (const float*)d_in[0];
    const float* W_ih = (const float*)d_in[1];
    const float* b_ih = (const float*)d_in[2];
    const float* W_hh = (const float*)d_in[3];
    const float* b_hh = (const float*)d_in[4];
    const float* W_fc = (const float*)d_in[5];
    const float* b_fc = (const float*)d_in[6];
    float* out = (float*)d_out;

    char* ws    = (char*)d_ws;
    u64*  xp    = (u64*)(ws + OFF_XP);
    u32*  wihb  = (u32*)(ws + OFF_WIHB);
    u64*  htag  = (u64*)(ws + OFF_HTAG);
    u32*  claim = (u32*)(ws + OFF_CLAIM);

    k_cvt_wih<<<dim3(N_H), dim3(256), 0, stream>>>(W_ih, wihb, claim);
    k_xproj<<<dim3(T_STEPS, 4), dim3(256), 0, stream>>>(x, wihb, b_ih, b_hh, xp);
    k_scan<<<dim3(G_LAUNCH), dim3(THREADS), 0, stream>>>(W_hh, xp, htag, claim, W_fc, b_fc, out);
}

// Round 3
// 17759.280 us; speedup vs baseline: 1.7806x; 1.7806x over previous
//
#include <hip/hip_runtime.h>
#include <hip/hip_bf16.h>
#include <stdint.h>

typedef unsigned int u32;
typedef unsigned long long u64;
typedef __attribute__((ext_vector_type(8))) short short8;
typedef __attribute__((ext_vector_type(4))) float floatx4;

#define T_STEPS 4096
#define BATCH   15
#define N_IN    512
#define N_H     1024
#define G_LAUNCH 64          // launched scan WGs; 8 elected (one XCD) participate
#define THREADS 512
#define HTAG_WORDS (15*512)  // tagged words per h buffer (15 batches x 512 pairs)
#define LDS_ROW 516          // u32 per h row: 512 + 4 pad

// ---------- ws layout (bytes) ----------
#define OFF_XP    0
#define OFF_WIHB  (134217728)
#define OFF_HTAG  (134217728 + 1048576)
#define OFF_CLAIM (134217728 + 1048576 + 2*HTAG_WORDS*8)   // u32[16]: 8 counters + winner

__device__ inline u32 f2bf1(float f) {            // fp32 -> bf16 (RNE), as u32
    u32 u = __builtin_bit_cast(u32, f);
    return (u + 0x7FFFu + ((u >> 16) & 1u)) >> 16;
}
__device__ inline float bf2f(u32 us) {            // bf16 (low 16) -> fp32
    return __builtin_bit_cast(float, us << 16);
}
__device__ inline float tanh_fast(float x) {
    float e = __expf(2.0f * x);                   // inf-safe at both ends
    return 1.0f - 2.0f / (e + 1.0f);
}
// Poll load: agent scope — served at the device coherence point (IC).
// Proven-correct; ~240cy/round empirically (34 rounds/step in baseline).
__device__ inline u64 mb_load(const u64* p) {
    return __hip_atomic_load(p, __ATOMIC_RELAXED, __HIP_MEMORY_SCOPE_AGENT);
}
// Publish: agent-scope atomic exchange (fire-and-forget swap_x2).
// R2 post-mortem: plain stores dwell dirty in the local L2 and drain to the
// IC lazily (~8000cy) — that drain WAS the step time. An agent-scope atomic
// executes at the coherence point directly, so the tagged word is visible to
// the agent-scope polls after ~1 IC round-trip instead of the lazy drain.
__device__ inline void pub_store(u64* p, u64 v) {
    __hip_atomic_exchange(p, v, __ATOMIC_RELAXED, __HIP_MEMORY_SCOPE_AGENT);
}

// ---------------- kernel 0: convert W_ih to packed bf16 (+ zero election block) ----------------
__global__ void k_cvt_wih(const float* __restrict__ W_ih, u32* __restrict__ wihb,
                          u32* __restrict__ claim) {
    if (blockIdx.x == 0 && threadIdx.x < 16) claim[threadIdx.x] = 0;
    int row = blockIdx.x;
    int tid = threadIdx.x;
    const float* p = W_ih + (size_t)row * N_IN + tid * 2;
    u32 packed = f2bf1(p[0]) | (f2bf1(p[1]) << 16);
    wihb[row * (N_IN / 2) + tid] = packed;
}

// ---------------- kernel 1: x_proj GEMM ----------------
// xp[((t*64 + cw)*64 + lane)] = bf16x4 (rows quad*4+i, col cw*16+(l&15))
__global__ void __launch_bounds__(256) k_xproj(
        const float* __restrict__ x, const u32* __restrict__ wihb,
        const float* __restrict__ b_ih, const float* __restrict__ b_hh,
        u64* __restrict__ xp) {
    const int t     = blockIdx.x;
    const int slice = blockIdx.y;
    const int tid   = threadIdx.x;
    const int wave  = tid >> 6;
    const int l     = tid & 63;
    const int row   = l & 15;       // batch
    const int quad  = l >> 4;
    const int colbase = slice * 256 + wave * 64;

    floatx4 acc[4] = {{0,0,0,0},{0,0,0,0},{0,0,0,0},{0,0,0,0}};
    const float* xrow = x + ((size_t)row * T_STEPS + t) * N_IN;

    #pragma unroll
    for (int kk = 0; kk < 16; ++kk) {
        short8 a;
        if (row < 15) {
            const float* pa = xrow + kk * 32 + quad * 8;
            float4 x0 = *(const float4*)(pa);
            float4 x1 = *(const float4*)(pa + 4);
            a[0]=(short)f2bf1(x0.x); a[1]=(short)f2bf1(x0.y); a[2]=(short)f2bf1(x0.z); a[3]=(short)f2bf1(x0.w);
            a[4]=(short)f2bf1(x1.x); a[5]=(short)f2bf1(x1.y); a[6]=(short)f2bf1(x1.z); a[7]=(short)f2bf1(x1.w);
        } else {
            #pragma unroll
            for (int j = 0; j < 8; ++j) a[j] = 0;
        }
        #pragma unroll
        for (int c4 = 0; c4 < 4; ++c4) {
            int col = colbase + c4 * 16 + (l & 15);
            const uint4* pb = (const uint4*)(wihb + (size_t)col * (N_IN/2) + kk * 16 + quad * 4);
            short8 b = __builtin_bit_cast(short8, *pb);
            acc[c4] = __builtin_amdgcn_mfma_f32_16x16x32_bf16(a, b, acc[c4], 0, 0, 0);
        }
    }
    #pragma unroll
    for (int c4 = 0; c4 < 4; ++c4) {
        int col = colbase + c4 * 16 + (l & 15);
        float bias = b_ih[col] + b_hh[col];
        u64 packed = (u64)f2bf1(acc[c4][0] + bias)
                   | ((u64)f2bf1(acc[c4][1] + bias) << 16)
                   | ((u64)f2bf1(acc[c4][2] + bias) << 32)
                   | ((u64)f2bf1(acc[c4][3] + bias) << 48);
        int cw = slice * 16 + wave * 4 + c4;
        xp[((size_t)t * 64 + cw) * 64 + l] = packed;
    }
}

// ---------------- kernel 2: sequential scan (8 elected WGs on ONE XCD) ----------------
__global__ void __launch_bounds__(THREADS, 2) k_scan(
        const float* __restrict__ W_hh, const u64* __restrict__ xp,
        u64* __restrict__ htag, u32* __restrict__ claim,
        const float* __restrict__ W_fc, const float* __restrict__ b_fc,
        float* __restrict__ out) {
    __shared__ u32 h_lds[2][16 * LDS_ROW];   // ping-pong h (bf16 pairs), row 15 = zero pad
    __shared__ float red[256];
    __shared__ int s_slot;
    __shared__ int s_dead;

    const int tid  = threadIdx.x;      // 0..511
    const int wave = tid >> 6;
    const int l    = tid & 63;
    const int c    = l & 15;           // col-in-tile (B/C role) == batch (A role)
    const int quad = l >> 4;

    // ---- XCD election: 8 co-XCD WGs win; others exit ----
    if (tid == 0) {
        u32 xcd;
        asm volatile("s_getreg_b32 %0, hwreg(HW_REG_XCC_ID)" : "=s"(xcd));
        xcd &= 7u;
        u32 slot = __hip_atomic_fetch_add(&claim[xcd], 1u, __ATOMIC_RELAXED,
                                          __HIP_MEMORY_SCOPE_AGENT);
        if (slot == 7u) {
            u32 exp = 0u;
            __hip_atomic_compare_exchange_strong(&claim[8], &exp, xcd + 1u,
                __ATOMIC_RELAXED, __ATOMIC_RELAXED, __HIP_MEMORY_SCOPE_AGENT);
        }
        u32 w = 0; int gg = 0;
        do { w = __hip_atomic_load(&claim[8], __ATOMIC_RELAXED, __HIP_MEMORY_SCOPE_AGENT); }
        while (!w && ++gg < (1 << 22));
        s_slot = (w == xcd + 1u && slot < 8u) ? (int)slot : -1;
        s_dead = 0;
    }
    __syncthreads();
    const int g = s_slot;              // 0..7 for participants
    if (g < 0) return;

    const int col  = g * 128 + wave * 16 + c;
    const int cw   = g * 8 + wave;

    // --- W_hh fragments permanently in registers ---
    short8 wf[32];
    {
        const float* wr = W_hh + (size_t)col * N_H;
        #pragma unroll
        for (int kk = 0; kk < 32; ++kk) {
            const float* p = wr + kk * 32 + quad * 8;
            float4 w0 = *(const float4*)(p);
            float4 w1 = *(const float4*)(p + 4);
            short8 bfr;
            bfr[0]=(short)f2bf1(w0.x); bfr[1]=(short)f2bf1(w0.y); bfr[2]=(short)f2bf1(w0.z); bfr[3]=(short)f2bf1(w0.w);
            bfr[4]=(short)f2bf1(w1.x); bfr[5]=(short)f2bf1(w1.y); bfr[6]=(short)f2bf1(w1.z); bfr[7]=(short)f2bf1(w1.w);
            wf[kk] = bfr;
        }
    }
    for (int i = tid; i < 2 * 16 * LDS_ROW; i += THREADS) ((u32*)h_lds)[i] = 0;
    __syncthreads();

    // ---- step 0: h(1) = tanh(xp(0)); publish tag 1 (parity 1) ----
    u64 xpw = xp[((size_t)0 * 64 + cw) * 64 + l];
    float h[4];
    {
        h[0] = tanh_fast(bf2f((u32)(xpw      ) & 0xFFFFu));
        h[1] = tanh_fast(bf2f((u32)(xpw >> 16) & 0xFFFFu));
        h[2] = tanh_fast(bf2f((u32)(xpw >> 32) & 0xFFFFu));
        h[3] = tanh_fast(bf2f((u32)(xpw >> 48) & 0xFFFFu));
        u64* bufw = htag + (size_t)1 * HTAG_WORDS;
        #pragma unroll
        for (int i = 0; i < 4; ++i) {
            int bt = quad * 4 + i;
            float o = __shfl_xor(h[i], 1);
            if (!(c & 1) && bt < 15) {
                u32 data = f2bf1(h[i]) | (f2bf1(o) << 16);
                pub_store(bufw + bt * 512 + (col >> 1), ((u64)1u << 32) | (u64)data);
            }
        }
    }
    u64 xpw_n = xp[((size_t)1 * 64 + cw) * 64 + l];

    for (int s = 1; s < T_STEPS; ++s) {
        xpw = xpw_n;
        const u64* buf = htag + (size_t)(s & 1) * HTAG_WORDS;
        u32* lds = &h_lds[s & 1][0];
        const u32 tag = (u32)s;

        // ---- poll: 15 agent-scope loads per thread, batched; per-word retry ----
        u64 v[15];
        #pragma unroll
        for (int j = 0; j < 15; ++j) v[j] = mb_load(buf + tid + j * 512);
        u32 got = 0;
        int rounds = 0;
        while (true) {
            #pragma unroll
            for (int j = 0; j < 15; ++j) {
                if (!((got >> j) & 1) && (u32)(v[j] >> 32) == tag) {
                    got |= 1u << j;
                    u32 w = (u32)tid + (u32)j * 512u;
                    lds[(w >> 9) * LDS_ROW + (w & 511)] = (u32)v[j];
                }
            }
            if (got == 0x7FFFu) break;
            if (++rounds > (1 << 20)) { s_dead = 1; break; }
            #pragma unroll
            for (int j = 0; j < 15; ++j)
                if (!((got >> j) & 1)) v[j] = mb_load(buf + tid + j * 512);
        }
        __syncthreads();               // the ONLY barrier per step
        if (s_dead) break;

        // ---- compute: fully-unrolled dual-accumulator MFMA chain ----
        floatx4 acc0, acc1;
        acc0[0] = bf2f((u32)(xpw      ) & 0xFFFFu);
        acc0[1] = bf2f((u32)(xpw >> 16) & 0xFFFFu);
        acc0[2] = bf2f((u32)(xpw >> 32) & 0xFFFFu);
        acc0[3] = bf2f((u32)(xpw >> 48) & 0xFFFFu);
        acc1[0] = 0.f; acc1[1] = 0.f; acc1[2] = 0.f; acc1[3] = 0.f;

        #pragma unroll
        for (int t = 0; t < 16; ++t) {
            uint4 a0 = *(const uint4*)&lds[c * LDS_ROW + (2 * t    ) * 16 + quad * 4];
            uint4 a1 = *(const uint4*)&lds[c * LDS_ROW + (2 * t + 1) * 16 + quad * 4];
            acc0 = __builtin_amdgcn_mfma_f32_16x16x32_bf16(
                       __builtin_bit_cast(short8, a0), wf[2 * t    ], acc0, 0, 0, 0);
            acc1 = __builtin_amdgcn_mfma_f32_16x16x32_bf16(
                       __builtin_bit_cast(short8, a1), wf[2 * t + 1], acc1, 0, 0, 0);
        }

        if (s + 1 < T_STEPS) xpw_n = xp[((size_t)(s + 1) * 64 + cw) * 64 + l];

        #pragma unroll
        for (int i = 0; i < 4; ++i) h[i] = tanh_fast(acc0[i] + acc1[i]);

        // ---- publish h(s+1): agent-scope atomic swaps -> visible at the IC ----
        u64* bufw = htag + (size_t)((s + 1) & 1) * HTAG_WORDS;
        const u32 tag1 = (u32)(s + 1);
        #pragma unroll
        for (int i = 0; i < 4; ++i) {
            int bt = quad * 4 + i;
            float o = __shfl_xor(h[i], 1);
            if (!(c & 1) && bt < 15) {
                u32 data = f2bf1(h[i]) | (f2bf1(o) << 16);
                pub_store(bufw + bt * 512 + (col >> 1), ((u64)tag1 << 32) | (u64)data);
            }
        }
    }

    // ---------------- epilogue: elected WG 0 computes the sigmoid head ----------------
    if (g == 0) {
        const u64* fbuf = htag + (size_t)(T_STEPS & 1) * HTAG_WORDS;  // parity 0
        const u32 ftag = (u32)T_STEPS;
        u32* lds = &h_lds[0][0];
        u64 v[15];
        #pragma unroll
        for (int j = 0; j < 15; ++j) v[j] = mb_load(fbuf + tid + j * 512);
        u32 got = 0;
        int rounds = 0;
        while (true) {
            #pragma unroll
            for (int j = 0; j < 15; ++j) {
                if (!((got >> j) & 1) && (u32)(v[j] >> 32) == ftag) {
                    got |= 1u << j;
                    u32 w = (u32)tid + (u32)j * 512u;
                    lds[(w >> 9) * LDS_ROW + (w & 511)] = (u32)v[j];
                }
            }
            if (got == 0x7FFFu) break;
            if (++rounds > (1 << 20)) break;
            #pragma unroll
            for (int j = 0; j < 15; ++j)
                if (!((got >> j) & 1)) v[j] = mb_load(fbuf + tid + j * 512);
        }
        __syncthreads();
        if (tid < 240) {
            int b = tid >> 4, seg = tid & 15;
            float sum = 0.f;
            for (int j = 0; j < 64; ++j) {
                int k = seg * 64 + j;
                u32 pr = lds[b * LDS_ROW + (k >> 1)];
                float hv = bf2f((pr >> ((k & 1) * 16)) & 0xFFFFu);
                sum += hv * W_fc[k];
            }
            red[tid] = sum;
        }
        __syncthreads();
        if (tid < 15) {
            float z = 0.f;
            #pragma unroll
            for (int j = 0; j < 16; ++j) z += red[tid * 16 + j];
            z += b_fc[0];
            out[tid] = 1.0f / (1.0f + __expf(-z));
        }
    }
}

extern "C" void kernel_launch(void* const* d_in, const int* in_sizes, int n_in,
                              void* d_out, int out_size, void* d_ws, size_t ws_size,
                              hipStream_t stream) {
    const float* x    = (const float*)d_in[0];
    const float* W_ih = (const float*)d_in[1];
    const float* b_ih = (const float*)d_in[2];
    const float* W_hh = (const float*)d_in[3];
    const float* b_hh = (const float*)d_in[4];
    const float* W_fc = (const float*)d_in[5];
    const float* b_fc = (const float*)d_in[6];
    float* out = (float*)d_out;

    char* ws    = (char*)d_ws;
    u64*  xp    = (u64*)(ws + OFF_XP);
    u32*  wihb  = (u32*)(ws + OFF_WIHB);
    u64*  htag  = (u64*)(ws + OFF_HTAG);
    u32*  claim = (u32*)(ws + OFF_CLAIM);

    k_cvt_wih<<<dim3(N_H), dim3(256), 0, stream>>>(W_ih, wihb, claim);
    k_xproj<<<dim3(T_STEPS, 4), dim3(256), 0, stream>>>(x, wihb, b_ih, b_hh, xp);
    k_scan<<<dim3(G_LAUNCH), dim3(THREADS), 0, stream>>>(W_hh, xp, htag, claim, W_fc, b_fc, out);
}

// Round 4
// 13012.848 us; speedup vs baseline: 2.4301x; 1.3647x over previous
//
#include <hip/hip_runtime.h>
#include <hip/hip_bf16.h>
#include <stdint.h>

typedef unsigned int u32;
typedef unsigned long long u64;
typedef __attribute__((ext_vector_type(8))) short short8;
typedef __attribute__((ext_vector_type(4))) float floatx4;

#define T_STEPS 4096
#define BATCH   15
#define N_IN    512
#define N_H     1024
#define G_LAUNCH 64          // launched scan WGs; 8 elected (one XCD) participate
#define THREADS 512
#define LDS_ROW 516          // u32 per h row: 512 + 4 pad

// ---------- ws layout (bytes) ----------
#define OFF_XP    0
#define OFF_WIHB  (134217728)
#define OFF_HBUF  (134217728 + 1048576)           // u32[2][16][512] = 64 KB (row 15 = zero pad)
#define OFF_FLAGS (134217728 + 1048576 + 65536)   // u64[8] @ 64B spacing = 512 B
#define OFF_CLAIM (134217728 + 1048576 + 65536 + 512)  // u32[16]: 8 counters + winner

__device__ inline u32 f2bf1(float f) {            // fp32 -> bf16 (RNE), as u32
    u32 u = __builtin_bit_cast(u32, f);
    return (u + 0x7FFFu + ((u >> 16) & 1u)) >> 16;
}
__device__ inline float bf2f(u32 us) {            // bf16 (low 16) -> fp32
    return __builtin_bit_cast(float, us << 16);
}
__device__ inline float tanh_fast(float x) {
    float e = __expf(2.0f * x);                   // inf-safe at both ends
    return 1.0f - 2.0f / (e + 1.0f);
}
// Agent-scope load: bypasses L1, hits the shared same-XCD L2 (proven: baseline
// exchange ran with ~zero EA traffic). Used for flag polls AND data reads.
__device__ inline u64 mb_load(const u64* p) {
    return __hip_atomic_load(p, __ATOMIC_RELAXED, __HIP_MEMORY_SCOPE_AGENT);
}
// Publish store: plain/workgroup scope — dirty line in the local XCD L2.
__device__ inline void pub_store32(u32* p, u32 v) {
    __hip_atomic_store(p, v, __ATOMIC_RELAXED, __HIP_MEMORY_SCOPE_WORKGROUP);
}
// Release fence: force all outstanding stores committed (acked by L2).
// This IS LLVM's agent-release on gfx9xx; baseline never fenced -> lazy drain.
__device__ inline void release_fence() {
    asm volatile("s_waitcnt vmcnt(0)" ::: "memory");
}

// ---------------- kernel 0: convert W_ih to packed bf16 (+ init claim/flags/zero-row) ----------------
__global__ void k_cvt_wih(const float* __restrict__ W_ih, u32* __restrict__ wihb,
                          u32* __restrict__ claim, u32* __restrict__ hbuf,
                          u64* __restrict__ fl) {
    int row = blockIdx.x;
    int tid = threadIdx.x;
    if (row == 0 && tid < 16) claim[tid] = 0;
    // flags: zero via agent-scope atomics (land at the coherence point, so a
    // fresh-launch L2 fetch can never observe pre-init garbage).
    if (row == 0 && tid >= 16 && tid < 24)
        __hip_atomic_exchange(fl + (size_t)(tid - 16) * 8, 0ull,
                              __ATOMIC_RELAXED, __HIP_MEMORY_SCOPE_AGENT);
    // hbuf batch-row 15 (both parities) must read as zero forever.
    if ((row == 1 || row == 2) && tid < 256) {
        u64* hz = (u64*)(hbuf + ((size_t)(row - 1) * 16 + 15) * 512);
        __hip_atomic_exchange(hz + tid, 0ull,
                              __ATOMIC_RELAXED, __HIP_MEMORY_SCOPE_AGENT);
    }
    const float* p = W_ih + (size_t)row * N_IN + tid * 2;
    u32 packed = f2bf1(p[0]) | (f2bf1(p[1]) << 16);
    wihb[row * (N_IN / 2) + tid] = packed;
}

// ---------------- kernel 1: x_proj GEMM ----------------
// xp[((t*64 + cw)*64 + lane)] = bf16x4 (rows quad*4+i, col cw*16+(l&15))
__global__ void __launch_bounds__(256) k_xproj(
        const float* __restrict__ x, const u32* __restrict__ wihb,
        const float* __restrict__ b_ih, const float* __restrict__ b_hh,
        u64* __restrict__ xp) {
    const int t     = blockIdx.x;
    const int slice = blockIdx.y;
    const int tid   = threadIdx.x;
    const int wave  = tid >> 6;
    const int l     = tid & 63;
    const int row   = l & 15;       // batch
    const int quad  = l >> 4;
    const int colbase = slice * 256 + wave * 64;

    floatx4 acc[4] = {{0,0,0,0},{0,0,0,0},{0,0,0,0},{0,0,0,0}};
    const float* xrow = x + ((size_t)row * T_STEPS + t) * N_IN;

    #pragma unroll
    for (int kk = 0; kk < 16; ++kk) {
        short8 a;
        if (row < 15) {
            const float* pa = xrow + kk * 32 + quad * 8;
            float4 x0 = *(const float4*)(pa);
            float4 x1 = *(const float4*)(pa + 4);
            a[0]=(short)f2bf1(x0.x); a[1]=(short)f2bf1(x0.y); a[2]=(short)f2bf1(x0.z); a[3]=(short)f2bf1(x0.w);
            a[4]=(short)f2bf1(x1.x); a[5]=(short)f2bf1(x1.y); a[6]=(short)f2bf1(x1.z); a[7]=(short)f2bf1(x1.w);
        } else {
            #pragma unroll
            for (int j = 0; j < 8; ++j) a[j] = 0;
        }
        #pragma unroll
        for (int c4 = 0; c4 < 4; ++c4) {
            int col = colbase + c4 * 16 + (l & 15);
            const uint4* pb = (const uint4*)(wihb + (size_t)col * (N_IN/2) + kk * 16 + quad * 4);
            short8 b = __builtin_bit_cast(short8, *pb);
            acc[c4] = __builtin_amdgcn_mfma_f32_16x16x32_bf16(a, b, acc[c4], 0, 0, 0);
        }
    }
    #pragma unroll
    for (int c4 = 0; c4 < 4; ++c4) {
        int col = colbase + c4 * 16 + (l & 15);
        float bias = b_ih[col] + b_hh[col];
        u64 packed = (u64)f2bf1(acc[c4][0] + bias)
                   | ((u64)f2bf1(acc[c4][1] + bias) << 16)
                   | ((u64)f2bf1(acc[c4][2] + bias) << 32)
                   | ((u64)f2bf1(acc[c4][3] + bias) << 48);
        int cw = slice * 16 + wave * 4 + c4;
        xp[((size_t)t * 64 + cw) * 64 + l] = packed;
    }
}

// ---------------- kernel 2: sequential scan (8 elected WGs on ONE XCD) ----------------
__global__ void __launch_bounds__(THREADS, 2) k_scan(
        const float* __restrict__ W_hh, const u64* __restrict__ xp,
        u32* __restrict__ hbuf, u64* __restrict__ fl, u32* __restrict__ claim,
        const float* __restrict__ W_fc, const float* __restrict__ b_fc,
        float* __restrict__ out) {
    __shared__ u32 h_lds[2][16 * LDS_ROW];   // ping-pong h (bf16 pairs), row 15 = zero pad
    __shared__ float red[256];
    __shared__ int s_slot;
    __shared__ int s_dead;

    const int tid  = threadIdx.x;      // 0..511
    const int wave = tid >> 6;
    const int l    = tid & 63;
    const int c    = l & 15;           // col-in-tile (B/C role) == batch (A role)
    const int quad = l >> 4;

    // ---- XCD election: 8 co-XCD WGs win; others exit ----
    if (tid == 0) {
        u32 xcd;
        asm volatile("s_getreg_b32 %0, hwreg(HW_REG_XCC_ID)" : "=s"(xcd));
        xcd &= 7u;
        u32 slot = __hip_atomic_fetch_add(&claim[xcd], 1u, __ATOMIC_RELAXED,
                                          __HIP_MEMORY_SCOPE_AGENT);
        if (slot == 7u) {
            u32 exp = 0u;
            __hip_atomic_compare_exchange_strong(&claim[8], &exp, xcd + 1u,
                __ATOMIC_RELAXED, __ATOMIC_RELAXED, __HIP_MEMORY_SCOPE_AGENT);
        }
        u32 w = 0; int gg = 0;
        do { w = __hip_atomic_load(&claim[8], __ATOMIC_RELAXED, __HIP_MEMORY_SCOPE_AGENT); }
        while (!w && ++gg < (1 << 22));
        s_slot = (w == xcd + 1u && slot < 8u) ? (int)slot : -1;
        s_dead = 0;
    }
    __syncthreads();
    const int g = s_slot;              // 0..7 for participants
    if (g < 0) return;

    const int col  = g * 128 + wave * 16 + c;
    const int cw   = g * 8 + wave;
    u64* myfl = fl + (size_t)g * 8;

    // --- W_hh fragments permanently in registers ---
    short8 wf[32];
    {
        const float* wr = W_hh + (size_t)col * N_H;
        #pragma unroll
        for (int kk = 0; kk < 32; ++kk) {
            const float* p = wr + kk * 32 + quad * 8;
            float4 w0 = *(const float4*)(p);
            float4 w1 = *(const float4*)(p + 4);
            short8 bfr;
            bfr[0]=(short)f2bf1(w0.x); bfr[1]=(short)f2bf1(w0.y); bfr[2]=(short)f2bf1(w0.z); bfr[3]=(short)f2bf1(w0.w);
            bfr[4]=(short)f2bf1(w1.x); bfr[5]=(short)f2bf1(w1.y); bfr[6]=(short)f2bf1(w1.z); bfr[7]=(short)f2bf1(w1.w);
            wf[kk] = bfr;
        }
    }
    for (int i = tid; i < 2 * 16 * LDS_ROW; i += THREADS) ((u32*)h_lds)[i] = 0;
    __syncthreads();

    // ---- step 0: h(1) = tanh(xp(0)); publish parity 1; flag = 1 ----
    u64 xpw = xp[((size_t)0 * 64 + cw) * 64 + l];
    float h[4];
    {
        h[0] = tanh_fast(bf2f((u32)(xpw      ) & 0xFFFFu));
        h[1] = tanh_fast(bf2f((u32)(xpw >> 16) & 0xFFFFu));
        h[2] = tanh_fast(bf2f((u32)(xpw >> 32) & 0xFFFFu));
        h[3] = tanh_fast(bf2f((u32)(xpw >> 48) & 0xFFFFu));
        u32* bufw = hbuf + (size_t)1 * (16 * 512);
        #pragma unroll
        for (int i = 0; i < 4; ++i) {
            int bt = quad * 4 + i;
            float o = __shfl_xor(h[i], 1);
            if (!(c & 1) && bt < 15) {
                u32 data = f2bf1(h[i]) | (f2bf1(o) << 16);
                pub_store32(bufw + bt * 512 + (col >> 1), data);
            }
        }
        release_fence();               // data committed in L2 ...
        __syncthreads();               // ... by ALL threads ...
        if (tid == 0)                  // ... before the flag goes up
            __hip_atomic_store(myfl, 1ull, __ATOMIC_RELAXED, __HIP_MEMORY_SCOPE_WORKGROUP);
    }
    u64 xpw_n = xp[((size_t)1 * 64 + cw) * 64 + l];

    for (int s = 1; s < T_STEPS; ++s) {
        xpw = xpw_n;
        const int par = s & 1;
        u32* lds = &h_lds[par][0];

        // ---- wait: poll the 8 producer flags only (8B/thread/round) ----
        {
            const u64 want = (u64)s;
            int rounds = 0;
            while (true) {
                u64 f = mb_load(fl + (size_t)(l & 7) * 8);
                if (__all((int)(f >= want))) break;
                if (++rounds > (1 << 20)) { s_dead = 1; break; }
            }
        }

        // ---- fetch h(s): 64B per thread, agent loads (L2 hits), into LDS ----
        {
            const u64* src = (const u64*)(hbuf + (size_t)par * (16 * 512)) + (size_t)tid * 8;
            u64 d0 = mb_load(src + 0), d1 = mb_load(src + 1);
            u64 d2 = mb_load(src + 2), d3 = mb_load(src + 3);
            u64 d4 = mb_load(src + 4), d5 = mb_load(src + 5);
            u64 d6 = mb_load(src + 6), d7 = mb_load(src + 7);
            u32* dst = lds + (tid >> 5) * LDS_ROW + (tid & 31) * 16;
            ((u64*)dst)[0] = d0; ((u64*)dst)[1] = d1;
            ((u64*)dst)[2] = d2; ((u64*)dst)[3] = d3;
            ((u64*)dst)[4] = d4; ((u64*)dst)[5] = d5;
            ((u64*)dst)[6] = d6; ((u64*)dst)[7] = d7;
        }
        __syncthreads();
        if (s_dead) break;

        // ---- compute: fully-unrolled dual-accumulator MFMA chain ----
        floatx4 acc0, acc1;
        acc0[0] = bf2f((u32)(xpw      ) & 0xFFFFu);
        acc0[1] = bf2f((u32)(xpw >> 16) & 0xFFFFu);
        acc0[2] = bf2f((u32)(xpw >> 32) & 0xFFFFu);
        acc0[3] = bf2f((u32)(xpw >> 48) & 0xFFFFu);
        acc1[0] = 0.f; acc1[1] = 0.f; acc1[2] = 0.f; acc1[3] = 0.f;

        #pragma unroll
        for (int t = 0; t < 16; ++t) {
            uint4 a0 = *(const uint4*)&lds[c * LDS_ROW + (2 * t    ) * 16 + quad * 4];
            uint4 a1 = *(const uint4*)&lds[c * LDS_ROW + (2 * t + 1) * 16 + quad * 4];
            acc0 = __builtin_amdgcn_mfma_f32_16x16x32_bf16(
                       __builtin_bit_cast(short8, a0), wf[2 * t    ], acc0, 0, 0, 0);
            acc1 = __builtin_amdgcn_mfma_f32_16x16x32_bf16(
                       __builtin_bit_cast(short8, a1), wf[2 * t + 1], acc1, 0, 0, 0);
        }

        if (s + 1 < T_STEPS) xpw_n = xp[((size_t)(s + 1) * 64 + cw) * 64 + l];

        #pragma unroll
        for (int i = 0; i < 4; ++i) h[i] = tanh_fast(acc0[i] + acc1[i]);

        // ---- publish h(s+1) -> parity (s+1)&1; fence; barrier; flag = s+1 ----
        u32* bufw = hbuf + (size_t)((s + 1) & 1) * (16 * 512);
        #pragma unroll
        for (int i = 0; i < 4; ++i) {
            int bt = quad * 4 + i;
            float o = __shfl_xor(h[i], 1);
            if (!(c & 1) && bt < 15) {
                u32 data = f2bf1(h[i]) | (f2bf1(o) << 16);
                pub_store32(bufw + bt * 512 + (col >> 1), data);
            }
        }
        release_fence();
        __syncthreads();
        if (tid == 0)
            __hip_atomic_store(myfl, (u64)(s + 1), __ATOMIC_RELAXED, __HIP_MEMORY_SCOPE_WORKGROUP);
    }

    // ---------------- epilogue: elected WG 0 computes the sigmoid head ----------------
    if (g == 0) {
        if (!s_dead) {
            const u64 want = (u64)T_STEPS;
            int rounds = 0;
            while (true) {
                u64 f = mb_load(fl + (size_t)(l & 7) * 8);
                if (__all((int)(f >= want))) break;
                if (++rounds > (1 << 20)) break;
            }
            u32* lds = &h_lds[0][0];
            const u64* src = (const u64*)(hbuf + (size_t)0) + (size_t)tid * 8;  // parity 0
            u64 d0 = mb_load(src + 0), d1 = mb_load(src + 1);
            u64 d2 = mb_load(src + 2), d3 = mb_load(src + 3);
            u64 d4 = mb_load(src + 4), d5 = mb_load(src + 5);
            u64 d6 = mb_load(src + 6), d7 = mb_load(src + 7);
            u32* dst = lds + (tid >> 5) * LDS_ROW + (tid & 31) * 16;
            ((u64*)dst)[0] = d0; ((u64*)dst)[1] = d1;
            ((u64*)dst)[2] = d2; ((u64*)dst)[3] = d3;
            ((u64*)dst)[4] = d4; ((u64*)dst)[5] = d5;
            ((u64*)dst)[6] = d6; ((u64*)dst)[7] = d7;
        }
        __syncthreads();
        u32* lds = &h_lds[0][0];
        if (tid < 240) {
            int b = tid >> 4, seg = tid & 15;
            float sum = 0.f;
            for (int j = 0; j < 64; ++j) {
                int k = seg * 64 + j;
                u32 pr = lds[b * LDS_ROW + (k >> 1)];
                float hv = bf2f((pr >> ((k & 1) * 16)) & 0xFFFFu);
                sum += hv * W_fc[k];
            }
            red[tid] = sum;
        }
        __syncthreads();
        if (tid < 15) {
            float z = 0.f;
            #pragma unroll
            for (int j = 0; j < 16; ++j) z += red[tid * 16 + j];
            z += b_fc[0];
            out[tid] = 1.0f / (1.0f + __expf(-z));
        }
    }
}

extern "C" void kernel_launch(void* const* d_in, const int* in_sizes, int n_in,
                              void* d_out, int out_size, void* d_ws, size_t ws_size,
                              hipStream_t stream) {
    const float* x    = (const float*)d_in[0];
    const float* W_ih = (const float*)d_in[1];
    const float* b_ih = (const float*)d_in[2];
    const float* W_hh = (const float*)d_in[3];
    const float* b_hh = (const float*)d_in[4];
    const float* W_fc = (const float*)d_in[5];
    const float* b_fc = (const float*)d_in[6];
    float* out = (float*)d_out;

    char* ws    = (char*)d_ws;
    u64*  xp    = (u64*)(ws + OFF_XP);
    u32*  wihb  = (u32*)(ws + OFF_WIHB);
    u32*  hbuf  = (u32*)(ws + OFF_HBUF);
    u64*  fl    = (u64*)(ws + OFF_FLAGS);
    u32*  claim = (u32*)(ws + OFF_CLAIM);

    k_cvt_wih<<<dim3(N_H), dim3(256), 0, stream>>>(W_ih, wihb, claim, hbuf, fl);
    k_xproj<<<dim3(T_STEPS, 4), dim3(256), 0, stream>>>(x, wihb, b_ih, b_hh, xp);
    k_scan<<<dim3(G_LAUNCH), dim3(THREADS), 0, stream>>>(W_hh, xp, hbuf, fl, claim, W_fc, b_fc, out);
}